// Round 14
// baseline (15760.744 us; speedup 1.0000x reference)
//
#include <hip/hip_runtime.h>
#include <hip/hip_bf16.h>
#include <math.h>

// ---------------- problem constants ----------------
#define S_LEN 2048
#define T_LEN 2048
#define HID   1024
#define GATES 4096
#define VOCAB 50257

typedef unsigned int u32;
typedef unsigned short u16;
typedef unsigned long long ull;
typedef u32 u32x4 __attribute__((ext_vector_type(4)));
typedef float f32x4 __attribute__((ext_vector_type(4)));
typedef short s16x8 __attribute__((ext_vector_type(8)));   // bf16x8 MFMA fragment

__device__ __forceinline__ float fsig_(float x)  { return 1.0f / (1.0f + __expf(-x)); }
__device__ __forceinline__ float ftanh_(float x) { float e = __expf(2.0f * x); return 1.0f - 2.0f / (e + 1.0f); }

__device__ __forceinline__ u32 bf16rne(float x) {
  u32 u = __float_as_uint(x);
  return (u + 0x7FFFu + ((u >> 16) & 1u)) >> 16;
}
__device__ __forceinline__ float bf16tof(u32 b) { return __uint_as_float(b << 16); }

// ---- software-pipelined poll of two packed 8B slots {tag(hi32), h(lo32)} ----
// Depth-2, vmcnt(2) retirement -> detection cadence ~RT/2 (R12, -0.33us/step).
__device__ __forceinline__ void pollpipe2(const ull* p0, const ull* p1, u32 want,
                                          ull& ra, ull& rb) {
  ull r0a, r0b, r1a, r1b, stmp;
  u32 par;
  const ull wantv = ((ull)want) << 32;
  asm volatile(
    "s_waitcnt vmcnt(0)\n\t"
    "global_load_dwordx2 %[r0a], %[p0], off sc0 sc1\n\t"
    "global_load_dwordx2 %[r0b], %[p1], off sc0 sc1\n\t"
    "1:\n\t"
    "global_load_dwordx2 %[r1a], %[p0], off sc0 sc1\n\t"
    "global_load_dwordx2 %[r1b], %[p1], off sc0 sc1\n\t"
    "s_waitcnt vmcnt(2)\n\t"
    "v_cmp_lt_u64 vcc, %[r0a], %[wv]\n\t"
    "s_mov_b64 %[st], vcc\n\t"
    "v_cmp_lt_u64 vcc, %[r0b], %[wv]\n\t"
    "s_or_b64 vcc, vcc, %[st]\n\t"
    "s_cbranch_vccz 2f\n\t"
    "global_load_dwordx2 %[r0a], %[p0], off sc0 sc1\n\t"
    "global_load_dwordx2 %[r0b], %[p1], off sc0 sc1\n\t"
    "s_waitcnt vmcnt(2)\n\t"
    "v_cmp_lt_u64 vcc, %[r1a], %[wv]\n\t"
    "s_mov_b64 %[st], vcc\n\t"
    "v_cmp_lt_u64 vcc, %[r1b], %[wv]\n\t"
    "s_or_b64 vcc, vcc, %[st]\n\t"
    "s_cbranch_vccz 3f\n\t"
    "s_branch 1b\n\t"
    "2:\n\t"
    "s_mov_b32 %[par], 0\n\t"
    "s_branch 4f\n\t"
    "3:\n\t"
    "s_mov_b32 %[par], 1\n\t"
    "4:\n\t"
    "s_waitcnt vmcnt(0)"
    : [r0a]"=&v"(r0a), [r0b]"=&v"(r0b), [r1a]"=&v"(r1a), [r1b]"=&v"(r1b),
      [st]"=&s"(stmp), [par]"=&s"(par)
    : [p0]"v"(p0), [p1]"v"(p1), [wv]"v"(wantv)
    : "vcc", "memory");
  ra = par ? r1a : r0a;
  rb = par ? r1b : r0b;
}

// ---- merged 4-slot pipelined poll (2 slots stream A + 2 slots stream B) ----
// One entry-drain + one pipeline instead of two sequential pollpipe2's: saves
// a serialized vmcnt(0)+RT from the L1 round each step. (HW-validated in R13:
// that round passed correctness; its regression was weight-spill, not this.)
__device__ __forceinline__ void pollpipe4(const ull* p0, const ull* p1, u32 wantA,
                                          const ull* q0, const ull* q1, u32 wantB,
                                          ull& ra, ull& rb, ull& rc, ull& rd) {
  ull r0a, r0b, r0c, r0d, r1a, r1b, r1c, r1d, stmp;
  u32 par;
  const ull wA = ((ull)wantA) << 32;
  const ull wB = ((ull)wantB) << 32;
  asm volatile(
    "s_waitcnt vmcnt(0)\n\t"
    "global_load_dwordx2 %[r0a], %[p0], off sc0 sc1\n\t"
    "global_load_dwordx2 %[r0b], %[p1], off sc0 sc1\n\t"
    "global_load_dwordx2 %[r0c], %[q0], off sc0 sc1\n\t"
    "global_load_dwordx2 %[r0d], %[q1], off sc0 sc1\n\t"
    "1:\n\t"
    "global_load_dwordx2 %[r1a], %[p0], off sc0 sc1\n\t"
    "global_load_dwordx2 %[r1b], %[p1], off sc0 sc1\n\t"
    "global_load_dwordx2 %[r1c], %[q0], off sc0 sc1\n\t"
    "global_load_dwordx2 %[r1d], %[q1], off sc0 sc1\n\t"
    "s_waitcnt vmcnt(4)\n\t"
    "v_cmp_lt_u64 vcc, %[r0a], %[wA]\n\t"
    "s_mov_b64 %[st], vcc\n\t"
    "v_cmp_lt_u64 vcc, %[r0b], %[wA]\n\t"
    "s_or_b64 %[st], vcc, %[st]\n\t"
    "v_cmp_lt_u64 vcc, %[r0c], %[wB]\n\t"
    "s_or_b64 %[st], vcc, %[st]\n\t"
    "v_cmp_lt_u64 vcc, %[r0d], %[wB]\n\t"
    "s_or_b64 vcc, vcc, %[st]\n\t"
    "s_cbranch_vccz 2f\n\t"
    "global_load_dwordx2 %[r0a], %[p0], off sc0 sc1\n\t"
    "global_load_dwordx2 %[r0b], %[p1], off sc0 sc1\n\t"
    "global_load_dwordx2 %[r0c], %[q0], off sc0 sc1\n\t"
    "global_load_dwordx2 %[r0d], %[q1], off sc0 sc1\n\t"
    "s_waitcnt vmcnt(4)\n\t"
    "v_cmp_lt_u64 vcc, %[r1a], %[wA]\n\t"
    "s_mov_b64 %[st], vcc\n\t"
    "v_cmp_lt_u64 vcc, %[r1b], %[wA]\n\t"
    "s_or_b64 %[st], vcc, %[st]\n\t"
    "v_cmp_lt_u64 vcc, %[r1c], %[wB]\n\t"
    "s_or_b64 %[st], vcc, %[st]\n\t"
    "v_cmp_lt_u64 vcc, %[r1d], %[wB]\n\t"
    "s_or_b64 vcc, vcc, %[st]\n\t"
    "s_cbranch_vccz 3f\n\t"
    "s_branch 1b\n\t"
    "2:\n\t"
    "s_mov_b32 %[par], 0\n\t"
    "s_branch 4f\n\t"
    "3:\n\t"
    "s_mov_b32 %[par], 1\n\t"
    "4:\n\t"
    "s_waitcnt vmcnt(0)"
    : [r0a]"=&v"(r0a), [r0b]"=&v"(r0b), [r0c]"=&v"(r0c), [r0d]"=&v"(r0d),
      [r1a]"=&v"(r1a), [r1b]"=&v"(r1b), [r1c]"=&v"(r1c), [r1d]"=&v"(r1d),
      [st]"=&s"(stmp), [par]"=&s"(par)
    : [p0]"v"(p0), [p1]"v"(p1), [q0]"v"(q0), [q1]"v"(q1),
      [wA]"v"(wA), [wB]"v"(wB)
    : "vcc", "memory");
  ra = par ? r1a : r0a;
  rb = par ? r1b : r0b;
  rc = par ? r1c : r0c;
  rd = par ? r1d : r0d;
}

// ---------------- tiny helpers ----------------
__global__ void zero_f4(float4* __restrict__ p, size_t n4) {
  size_t i = (size_t)blockIdx.x * blockDim.x + threadIdx.x;
  size_t stride = (size_t)gridDim.x * blockDim.x;
  for (; i < n4; i += stride) p[i] = make_float4(0.f, 0.f, 0.f, 0.f);
}

__global__ void build_dec_tokens(const int* __restrict__ outputs, const int* __restrict__ sos,
                                 int* __restrict__ toks, int T) {
  int t = blockIdx.x * blockDim.x + threadIdx.x;
  if (t < T) toks[t] = (t == 0) ? sos[0] : outputs[t - 1];
}

// split f32 -> bf16 hi + bf16 lo (residual), RNE
__global__ void xsplit(const float* __restrict__ x, u16* __restrict__ hi,
                       u16* __restrict__ lo, int n) {
  int i = blockIdx.x * 256 + threadIdx.x;
  if (i < n) {
    float v = x[i];
    u32 h = bf16rne(v);
    hi[i] = (u16)h;
    lo[i] = (u16)bf16rne(v - bf16tof(h));
  }
}

// ---------------- split-bf16 MFMA logits GEMM (R12-proven) ----------------
__global__ __launch_bounds__(256) void gemm_logits(
    const u16* __restrict__ Xhi, const u16* __restrict__ Xlo,
    const float* __restrict__ W, const float* __restrict__ b,
    float* __restrict__ C, int M, int N, int K)
{
  __shared__ u16 Bhi[64][40];
  __shared__ u16 Blo[64][40];
  const int tid = threadIdx.x;
  const int wv  = tid >> 6;
  const int l   = tid & 63;
  const int l15 = l & 15;
  const int kro = (l >> 4) * 8;
  const int m0  = blockIdx.y * 128;
  const int n0  = blockIdx.x * 64;
  const int srow = tid >> 2;
  const int skp  = (tid & 3) * 8;

  f32x4 acc[2][4] = {};

  for (int k0 = 0; k0 < K; k0 += 32) {
    float w[8] = {0.f};
    {
      int wr = n0 + srow;
      if (wr < N) {
        const float4 a = *(const float4*)(W + (size_t)wr * K + k0 + skp);
        const float4 c = *(const float4*)(W + (size_t)wr * K + k0 + skp + 4);
        w[0] = a.x; w[1] = a.y; w[2] = a.z; w[3] = a.w;
        w[4] = c.x; w[5] = c.y; w[6] = c.z; w[7] = c.w;
      }
    }
    __syncthreads();
#pragma unroll
    for (int e = 0; e < 8; ++e) {
      u32 h = bf16rne(w[e]);
      Bhi[srow][skp + e] = (u16)h;
      Blo[srow][skp + e] = (u16)bf16rne(w[e] - bf16tof(h));
    }
    __syncthreads();

    const size_t xoff0 = (size_t)(m0 + wv * 32 + l15) * K + k0 + kro;
    const size_t xoff1 = xoff0 + (size_t)16 * K;
    s16x8 ah0 = *(const s16x8*)(Xhi + xoff0);
    s16x8 al0 = *(const s16x8*)(Xlo + xoff0);
    s16x8 ah1 = *(const s16x8*)(Xhi + xoff1);
    s16x8 al1 = *(const s16x8*)(Xlo + xoff1);
#pragma unroll
    for (int tn = 0; tn < 4; ++tn) {
      s16x8 bh = *(const s16x8*)&Bhi[tn * 16 + l15][kro];
      s16x8 bl = *(const s16x8*)&Blo[tn * 16 + l15][kro];
      acc[0][tn] = __builtin_amdgcn_mfma_f32_16x16x32_bf16(ah0, bh, acc[0][tn], 0, 0, 0);
      acc[0][tn] = __builtin_amdgcn_mfma_f32_16x16x32_bf16(al0, bh, acc[0][tn], 0, 0, 0);
      acc[0][tn] = __builtin_amdgcn_mfma_f32_16x16x32_bf16(ah0, bl, acc[0][tn], 0, 0, 0);
      acc[1][tn] = __builtin_amdgcn_mfma_f32_16x16x32_bf16(ah1, bh, acc[1][tn], 0, 0, 0);
      acc[1][tn] = __builtin_amdgcn_mfma_f32_16x16x32_bf16(al1, bh, acc[1][tn], 0, 0, 0);
      acc[1][tn] = __builtin_amdgcn_mfma_f32_16x16x32_bf16(ah1, bl, acc[1][tn], 0, 0, 0);
    }
  }

#pragma unroll
  for (int tm = 0; tm < 2; ++tm)
#pragma unroll
    for (int tn = 0; tn < 4; ++tn) {
      int n = n0 + tn * 16 + l15;
      if (n < N) {
        float bias = b[n];
#pragma unroll
        for (int r = 0; r < 4; ++r) {
          int m = m0 + wv * 32 + tm * 16 + (l >> 4) * 4 + r;
          C[(size_t)m * N + n] = acc[tm][tn][r] + bias;
        }
      }
    }
}

// ---------------- fused 2-layer persistent LSTM (R12 structure) ----------------
// 256 WGs x 512 threads (1 WG/CU). wg<128 layer 0 (x = embedding rows, LDS
// double-buffer prefetch); wg>=128 layer 1 (x = L0 h, 1-step skew). Fused
// Wi@x + Wh@h: 8 units/WG, 32 gate rows, 16 lanes/row; weights streamed by
// compiler loads (L1/L2-resident -- 3 rounds of residency attempts all lost:
// remat (R10), AGPR-read tax (R11), scratch spill (R13)). Exchange: write-once
// packed 8B slots {tag=t+1 (hi32), f32 h (lo32)}. ONLY change vs R12: L1's two
// sequential pipelined polls merged into pollpipe4 (one entry drain, 4 loads
// in flight) -- L1 does strictly more work per round than L0 and likely sets
// the dispatch period.
__global__ __launch_bounds__(512, 1) void lstm2(
    const float* __restrict__ emb,  const int* __restrict__ toks,
    const float* __restrict__ Wi0,  const float* __restrict__ Wh0,
    const float* __restrict__ bi0,  const float* __restrict__ bh0,
    const float* __restrict__ Wi1,  const float* __restrict__ Wh1,
    const float* __restrict__ bi1,  const float* __restrict__ bh1,
    const float* __restrict__ h00,  const float* __restrict__ c00,
    const float* __restrict__ h01,  const float* __restrict__ c01,
    ull* __restrict__ s0, ull* __restrict__ s1,   // [T][1024] packed slots
    float* __restrict__ hf0, float* __restrict__ cf0,
    float* __restrict__ hf1, float* __restrict__ cf1,
    float* __restrict__ dec_out, int T)
{
  const int tid = threadIdx.x;
  const int wg  = blockIdx.x;
  const bool isL0 = (wg < 128);
  const int wgl = isL0 ? wg : wg - 128;

  const int lane16 = tid & 15;
  const int rloc = tid >> 4;            // 0..31 local gate row
  const int jloc = rloc & 7;
  const int gate = rloc >> 3;           // i,f,g,o
  const int grow = gate * HID + wgl * 8 + jloc;

  __shared__ float lds_x[2][HID];
  __shared__ float lds_h[HID];
  __shared__ float lds_g[32];
  __shared__ float lds_c[8];

  const float* Wi = isL0 ? Wi0 : Wi1;
  const float* Wh = isL0 ? Wh0 : Wh1;
  const float breg = (isL0 ? (bi0[grow] + bh0[grow]) : (bi1[grow] + bh1[grow]));

  f32x4 Wir[16], Whr[16];
  {
    const f32x4* wi = (const f32x4*)(Wi + (size_t)grow * HID);
    const f32x4* wh = (const f32x4*)(Wh + (size_t)grow * HID);
#pragma unroll
    for (int i = 0; i < 16; ++i) {
      Wir[i] = wi[lane16 + i * 16];
      Whr[i] = wh[lane16 + i * 16];
    }
  }

  {
    const float* hini = isL0 ? h00 : h01;
    const float* cini = isL0 ? c00 : c01;
    if (tid < 8) lds_c[tid] = cini[wgl * 8 + tid];
    if (tid < 256) ((float4*)lds_h)[tid] = ((const float4*)hini)[tid];
    if (isL0 && tid < 256) {
      int tok = toks[0];
      ((float4*)lds_x[0])[tid] = ((const float4*)(emb + (size_t)tok * HID))[tid];
    }
  }
  __syncthreads();

  ull* s_mine = isL0 ? s0 : s1;

  for (int t = 0; t < T; ++t) {
    const int cur = t & 1;

    // ---- stage step inputs via pipelined polls ----
    if (isL0) {
      if (t > 0) {
        ull va, vb;
        pollpipe2(s0 + (size_t)(t - 1) * HID + 2 * tid,
                  s0 + (size_t)(t - 1) * HID + 2 * tid + 1, (u32)t, va, vb);
        lds_h[2 * tid]     = __uint_as_float((u32)va);
        lds_h[2 * tid + 1] = __uint_as_float((u32)vb);
      }
    } else {
      if (t == 0) {
        ull va, vb;
        pollpipe2(s0 + 2 * tid, s0 + 2 * tid + 1, 1u, va, vb);
        lds_x[0][2 * tid]     = __uint_as_float((u32)va);
        lds_x[0][2 * tid + 1] = __uint_as_float((u32)vb);
      } else {
        ull va, vb, vc, vd;
        pollpipe4(s0 + (size_t)t * HID + 2 * tid,
                  s0 + (size_t)t * HID + 2 * tid + 1, (u32)(t + 1),
                  s1 + (size_t)(t - 1) * HID + 2 * tid,
                  s1 + (size_t)(t - 1) * HID + 2 * tid + 1, (u32)t,
                  va, vb, vc, vd);
        lds_x[0][2 * tid]     = __uint_as_float((u32)va);
        lds_x[0][2 * tid + 1] = __uint_as_float((u32)vb);
        lds_h[2 * tid]        = __uint_as_float((u32)vc);
        lds_h[2 * tid + 1]    = __uint_as_float((u32)vd);
      }
    }
    __syncthreads();

    // L0: prefetch x_{t+1} after the poll barrier (retires under compute)
    if (isL0 && tid < 256 && t + 1 < T) {
      int tok = toks[t + 1];
      ((float4*)lds_x[cur ^ 1])[tid] = ((const float4*)(emb + (size_t)tok * HID))[tid];
    }

    // ---- fused gate dot: Wi@x + Wh@h ----
    const float* xbuf = isL0 ? lds_x[cur] : lds_x[0];
    float p0 = 0.f, p1 = 0.f, p2 = 0.f, p3 = 0.f;
#pragma unroll
    for (int i = 0; i < 16; ++i) {
      const float4 xv = *(const float4*)&xbuf[(lane16 << 2) + (i << 6)];
      p0 = fmaf(Wir[i].x, xv.x, p0);
      p1 = fmaf(Wir[i].y, xv.y, p1);
      p2 = fmaf(Wir[i].z, xv.z, p2);
      p3 = fmaf(Wir[i].w, xv.w, p3);
    }
#pragma unroll
    for (int i = 0; i < 16; ++i) {
      const float4 hv = *(const float4*)&lds_h[(lane16 << 2) + (i << 6)];
      p0 = fmaf(Whr[i].x, hv.x, p0);
      p1 = fmaf(Whr[i].y, hv.y, p1);
      p2 = fmaf(Whr[i].z, hv.z, p2);
      p3 = fmaf(Whr[i].w, hv.w, p3);
    }
    float sum = (p0 + p1) + (p2 + p3);
    sum += __shfl_xor(sum, 1);
    sum += __shfl_xor(sum, 2);
    sum += __shfl_xor(sum, 4);
    sum += __shfl_xor(sum, 8);
    if (lane16 == 0) lds_g[rloc] = sum + breg;
    __syncthreads();

    // ---- gate epilogue + packed publish ----
    if (tid < 8) {
      const float gi = lds_g[tid];
      const float gf = lds_g[8 + tid];
      const float gg = lds_g[16 + tid];
      const float go = lds_g[24 + tid];
      const float c = fsig_(gf) * lds_c[tid] + fsig_(gi) * ftanh_(gg);
      const float h = fsig_(go) * ftanh_(c);
      lds_c[tid] = c;
      const int col = wgl * 8 + tid;
      const ull pk = ((ull)(u32)(t + 1) << 32) | (ull)__float_as_uint(h);
      __hip_atomic_store(&s_mine[(size_t)t * HID + col], pk,
                         __ATOMIC_RELAXED, __HIP_MEMORY_SCOPE_AGENT);
      if (!isL0 && dec_out) dec_out[(size_t)t * HID + col] = h;
      if (t == T - 1) {
        if (isL0) { if (hf0) hf0[col] = h; if (cf0) cf0[col] = c; }
        else      { if (hf1) hf1[col] = h; if (cf1) cf1[col] = c; }
      }
    }
    // no trailing barrier: next step's post-poll barrier orders LDS reuse
  }
}

// ---------------- launch ----------------
extern "C" void kernel_launch(void* const* d_in, const int* in_sizes, int n_in,
                              void* d_out, int out_size, void* d_ws, size_t ws_size,
                              hipStream_t stream) {
  const int*   inputs  = (const int*)d_in[0];
  const int*   outputs = (const int*)d_in[1];
  const int*   sos     = (const int*)d_in[2];
  const float* enc_emb = (const float*)d_in[3];
  const float* dec_emb = (const float*)d_in[4];
  const float* enc_Wih = (const float*)d_in[5];
  const float* enc_Whh = (const float*)d_in[6];
  const float* enc_bih = (const float*)d_in[7];
  const float* enc_bhh = (const float*)d_in[8];
  const float* dec_Wih = (const float*)d_in[9];
  const float* dec_Whh = (const float*)d_in[10];
  const float* dec_bih = (const float*)d_in[11];
  const float* dec_bhh = (const float*)d_in[12];
  const float* lin_W   = (const float*)d_in[13];
  const float* lin_b   = (const float*)d_in[14];

  float* out = (float*)d_out;
  // d_out scratch: 4 packed streams (16 MB each), all dead before logits GEMM.
  ull* s0e = (ull*)d_out;
  ull* s1e = s0e + 2097152;
  ull* s0d = s1e + 2097152;
  ull* s1d = s0d + 2097152;

  char* ws = (char*)d_ws;
  float* zerosv = (float*)(ws + 0);
  float* hf0    = (float*)(ws + 4096);
  float* cf0    = (float*)(ws + 8192);
  float* hf1    = (float*)(ws + 12288);
  float* cf1    = (float*)(ws + 16384);
  int*   dtoks  = (int*)(ws + 20480);
  float* B2     = (float*)(ws + ((size_t)1 << 20));    // 8 MB: dec_out f32
  u16*   Xhi    = (u16*)(ws + ((size_t)10 << 20));     // 4 MB
  u16*   Xlo    = (u16*)(ws + ((size_t)15 << 20));     // 4 MB

  const size_t WOFF = (size_t)GATES * HID;

  // zero stream tags (64 MB in d_out) + zeros vector; every call (graph replay)
  zero_f4<<<2048, 256, 0, stream>>>((float4*)d_out, 4194304);
  zero_f4<<<1, 256, 0, stream>>>((float4*)zerosv, 256);
  build_dec_tokens<<<8, 256, 0, stream>>>(outputs, sos, dtoks, T_LEN);

  // encoder: both layers, fused Wi@x, layer-pipelined
  lstm2<<<256, 512, 0, stream>>>(
      enc_emb, inputs,
      enc_Wih, enc_Whh, enc_bih, enc_bhh,
      enc_Wih + WOFF, enc_Whh + WOFF, enc_bih + GATES, enc_bhh + GATES,
      zerosv, zerosv, zerosv, zerosv,
      s0e, s1e, hf0, cf0, hf1, cf1, nullptr, S_LEN);

  // decoder: init from encoder finals; layer-1 h also written plain to B2
  lstm2<<<256, 512, 0, stream>>>(
      dec_emb, dtoks,
      dec_Wih, dec_Whh, dec_bih, dec_bhh,
      dec_Wih + WOFF, dec_Whh + WOFF, dec_bih + GATES, dec_bhh + GATES,
      hf0, cf0, hf1, cf1,
      s0d, s1d, nullptr, nullptr, nullptr, nullptr, B2, T_LEN);

  // logits: split X to bf16 hi/lo, then 3-term split-bf16 MFMA GEMM
  xsplit<<<(T_LEN * HID + 255) / 256, 256, 0, stream>>>(B2, Xhi, Xlo, T_LEN * HID);
  dim3 gemmV_grid((VOCAB + 63) / 64, T_LEN / 128);
  gemm_logits<<<gemmV_grid, 256, 0, stream>>>(Xhi, Xlo, lin_W, lin_b, out,
                                              T_LEN, VOCAB, HID);
}

// Round 15
// 13300.449 us; speedup vs baseline: 1.1850x; 1.1850x over previous
//
#include <hip/hip_runtime.h>
#include <hip/hip_bf16.h>
#include <math.h>

// ---------------- problem constants ----------------
#define S_LEN 2048
#define T_LEN 2048
#define HID   1024
#define GATES 4096
#define VOCAB 50257
#define SLOTS 512            // packed slots per step: {tag(hi32), 2xbf16(lo32)}

typedef unsigned int u32;
typedef unsigned short u16;
typedef unsigned long long ull;
typedef float f32x4 __attribute__((ext_vector_type(4)));
typedef short s16x8 __attribute__((ext_vector_type(8)));   // bf16x8 MFMA fragment

__device__ __forceinline__ float fsig_(float x)  { return 1.0f / (1.0f + __expf(-x)); }
__device__ __forceinline__ float ftanh_(float x) { float e = __expf(2.0f * x); return 1.0f - 2.0f / (e + 1.0f); }

__device__ __forceinline__ u32 bf16rne(float x) {
  u32 u = __float_as_uint(x);
  return (u + 0x7FFFu + ((u >> 16) & 1u)) >> 16;
}
__device__ __forceinline__ float bf16tof(u32 b) { return __uint_as_float(b << 16); }

// ---- depth-2 software-pipelined poll of ONE packed 8B slot ----
// 2 loads in flight on one address; vmcnt(1) retires the oldest each half-RT.
// Tag+data checked atomically: slot_u64 < (want<<32) iff tag < want.
// Exit is wave-uniform (vccz = all 64 lanes ready) -- the barrier needs that
// anyway. Entry vmcnt(0) drains unrelated vmem so counting is exact.
__device__ __forceinline__ ull pollpipe1(const ull* p, u32 want) {
  ull r0, r1;
  u32 par;
  const ull wantv = ((ull)want) << 32;
  asm volatile(
    "s_waitcnt vmcnt(0)\n\t"
    "global_load_dwordx2 %[r0], %[p], off sc0 sc1\n\t"
    "1:\n\t"
    "global_load_dwordx2 %[r1], %[p], off sc0 sc1\n\t"
    "s_waitcnt vmcnt(1)\n\t"
    "v_cmp_lt_u64 vcc, %[r0], %[wv]\n\t"
    "s_cbranch_vccz 2f\n\t"
    "global_load_dwordx2 %[r0], %[p], off sc0 sc1\n\t"
    "s_waitcnt vmcnt(1)\n\t"
    "v_cmp_lt_u64 vcc, %[r1], %[wv]\n\t"
    "s_cbranch_vccz 3f\n\t"
    "s_branch 1b\n\t"
    "2:\n\t"
    "s_mov_b32 %[par], 0\n\t"
    "s_branch 4f\n\t"
    "3:\n\t"
    "s_mov_b32 %[par], 1\n\t"
    "4:\n\t"
    "s_waitcnt vmcnt(0)"
    : [r0]"=&v"(r0), [r1]"=&v"(r1), [par]"=&s"(par)
    : [p]"v"(p), [wv]"v"(wantv)
    : "vcc", "memory");
  return par ? r1 : r0;
}

// ---- x-poll with h-slot preload (L1's staging) ----
// The h slot (usually already published) is loaded ONCE at pipeline entry and
// retires with the first vmcnt(1) -- zero added latency, zero repeated polling
// (R14's failure: merged re-issue of satisfied slots doubled fabric traffic).
// Caller checks vh's tag afterward; rare miss -> pollpipe1 on it.
__device__ __forceinline__ ull pollpipe1h(const ull* p, u32 want,
                                          const ull* q, ull& vh) {
  ull r0, r1;
  u32 par;
  const ull wantv = ((ull)want) << 32;
  asm volatile(
    "s_waitcnt vmcnt(0)\n\t"
    "global_load_dwordx2 %[vh], %[q], off sc0 sc1\n\t"
    "global_load_dwordx2 %[r0], %[p], off sc0 sc1\n\t"
    "1:\n\t"
    "global_load_dwordx2 %[r1], %[p], off sc0 sc1\n\t"
    "s_waitcnt vmcnt(1)\n\t"
    "v_cmp_lt_u64 vcc, %[r0], %[wv]\n\t"
    "s_cbranch_vccz 2f\n\t"
    "global_load_dwordx2 %[r0], %[p], off sc0 sc1\n\t"
    "s_waitcnt vmcnt(1)\n\t"
    "v_cmp_lt_u64 vcc, %[r1], %[wv]\n\t"
    "s_cbranch_vccz 3f\n\t"
    "s_branch 1b\n\t"
    "2:\n\t"
    "s_mov_b32 %[par], 0\n\t"
    "s_branch 4f\n\t"
    "3:\n\t"
    "s_mov_b32 %[par], 1\n\t"
    "4:\n\t"
    "s_waitcnt vmcnt(0)"
    : [r0]"=&v"(r0), [r1]"=&v"(r1), [par]"=&s"(par), [vh]"=&v"(vh)
    : [p]"v"(p), [wv]"v"(wantv), [q]"v"(q)
    : "vcc", "memory");
  return par ? r1 : r0;
}

// ---------------- tiny helpers ----------------
__global__ void zero_f4(float4* __restrict__ p, size_t n4) {
  size_t i = (size_t)blockIdx.x * blockDim.x + threadIdx.x;
  size_t stride = (size_t)gridDim.x * blockDim.x;
  for (; i < n4; i += stride) p[i] = make_float4(0.f, 0.f, 0.f, 0.f);
}

__global__ void build_dec_tokens(const int* __restrict__ outputs, const int* __restrict__ sos,
                                 int* __restrict__ toks, int T) {
  int t = blockIdx.x * blockDim.x + threadIdx.x;
  if (t < T) toks[t] = (t == 0) ? sos[0] : outputs[t - 1];
}

// split f32 -> bf16 hi + bf16 lo (residual), RNE
__global__ void xsplit(const float* __restrict__ x, u16* __restrict__ hi,
                       u16* __restrict__ lo, int n) {
  int i = blockIdx.x * 256 + threadIdx.x;
  if (i < n) {
    float v = x[i];
    u32 h = bf16rne(v);
    hi[i] = (u16)h;
    lo[i] = (u16)bf16rne(v - bf16tof(h));
  }
}

// ---------------- split-bf16 MFMA logits GEMM (R12-proven) ----------------
__global__ __launch_bounds__(256) void gemm_logits(
    const u16* __restrict__ Xhi, const u16* __restrict__ Xlo,
    const float* __restrict__ W, const float* __restrict__ b,
    float* __restrict__ C, int M, int N, int K)
{
  __shared__ u16 Bhi[64][40];
  __shared__ u16 Blo[64][40];
  const int tid = threadIdx.x;
  const int wv  = tid >> 6;
  const int l   = tid & 63;
  const int l15 = l & 15;
  const int kro = (l >> 4) * 8;
  const int m0  = blockIdx.y * 128;
  const int n0  = blockIdx.x * 64;
  const int srow = tid >> 2;
  const int skp  = (tid & 3) * 8;

  f32x4 acc[2][4] = {};

  for (int k0 = 0; k0 < K; k0 += 32) {
    float w[8] = {0.f};
    {
      int wr = n0 + srow;
      if (wr < N) {
        const float4 a = *(const float4*)(W + (size_t)wr * K + k0 + skp);
        const float4 c = *(const float4*)(W + (size_t)wr * K + k0 + skp + 4);
        w[0] = a.x; w[1] = a.y; w[2] = a.z; w[3] = a.w;
        w[4] = c.x; w[5] = c.y; w[6] = c.z; w[7] = c.w;
      }
    }
    __syncthreads();
#pragma unroll
    for (int e = 0; e < 8; ++e) {
      u32 h = bf16rne(w[e]);
      Bhi[srow][skp + e] = (u16)h;
      Blo[srow][skp + e] = (u16)bf16rne(w[e] - bf16tof(h));
    }
    __syncthreads();

    const size_t xoff0 = (size_t)(m0 + wv * 32 + l15) * K + k0 + kro;
    const size_t xoff1 = xoff0 + (size_t)16 * K;
    s16x8 ah0 = *(const s16x8*)(Xhi + xoff0);
    s16x8 al0 = *(const s16x8*)(Xlo + xoff0);
    s16x8 ah1 = *(const s16x8*)(Xhi + xoff1);
    s16x8 al1 = *(const s16x8*)(Xlo + xoff1);
#pragma unroll
    for (int tn = 0; tn < 4; ++tn) {
      s16x8 bh = *(const s16x8*)&Bhi[tn * 16 + l15][kro];
      s16x8 bl = *(const s16x8*)&Blo[tn * 16 + l15][kro];
      acc[0][tn] = __builtin_amdgcn_mfma_f32_16x16x32_bf16(ah0, bh, acc[0][tn], 0, 0, 0);
      acc[0][tn] = __builtin_amdgcn_mfma_f32_16x16x32_bf16(al0, bh, acc[0][tn], 0, 0, 0);
      acc[0][tn] = __builtin_amdgcn_mfma_f32_16x16x32_bf16(ah0, bl, acc[0][tn], 0, 0, 0);
      acc[1][tn] = __builtin_amdgcn_mfma_f32_16x16x32_bf16(ah1, bh, acc[1][tn], 0, 0, 0);
      acc[1][tn] = __builtin_amdgcn_mfma_f32_16x16x32_bf16(al1, bh, acc[1][tn], 0, 0, 0);
      acc[1][tn] = __builtin_amdgcn_mfma_f32_16x16x32_bf16(ah1, bl, acc[1][tn], 0, 0, 0);
    }
  }

#pragma unroll
  for (int tm = 0; tm < 2; ++tm)
#pragma unroll
    for (int tn = 0; tn < 4; ++tn) {
      int n = n0 + tn * 16 + l15;
      if (n < N) {
        float bias = b[n];
#pragma unroll
        for (int r = 0; r < 4; ++r) {
          int m = m0 + wv * 32 + tm * 16 + (l >> 4) * 4 + r;
          C[(size_t)m * N + n] = acc[tm][tn][r] + bias;
        }
      }
    }
}

// ---------------- fused 2-layer persistent LSTM (R12 structure, bf16 slots) ----
// 256 WGs x 512 threads (1 WG/CU). wg<128 layer 0 (x = embedding rows, LDS
// double-buffer prefetch); wg>=128 layer 1 (x = L0 h, 1-step skew). Fused
// Wi@x + Wh@h: 8 units/WG, 32 gate rows, 16 lanes/row; weights streamed by
// compiler loads (3 residency attempts all lost: remat R10 / AGPR tax R11 /
// spill R13). Exchange: write-once streams of SLOTS=512 packed 8B slots
// {tag=t+1 (hi32), 2xbf16 h (lo32)} (bf16 exchange HW-validated in R9, same
// absmax). Each thread polls ONE slot -> half R12's poll traffic. L1: h-slot
// preloaded at the x-poll's entry (zero-latency check, no repeated polling --
// the R14 traffic lesson); rare miss falls back to a real poll.
__global__ __launch_bounds__(512, 1) void lstm2(
    const float* __restrict__ emb,  const int* __restrict__ toks,
    const float* __restrict__ Wi0,  const float* __restrict__ Wh0,
    const float* __restrict__ bi0,  const float* __restrict__ bh0,
    const float* __restrict__ Wi1,  const float* __restrict__ Wh1,
    const float* __restrict__ bi1,  const float* __restrict__ bh1,
    const float* __restrict__ h00,  const float* __restrict__ c00,
    const float* __restrict__ h01,  const float* __restrict__ c01,
    ull* __restrict__ s0, ull* __restrict__ s1,   // [T][SLOTS]
    float* __restrict__ hf0, float* __restrict__ cf0,
    float* __restrict__ hf1, float* __restrict__ cf1,
    float* __restrict__ dec_out, int T)
{
  const int tid = threadIdx.x;
  const int wg  = blockIdx.x;
  const bool isL0 = (wg < 128);
  const int wgl = isL0 ? wg : wg - 128;

  const int lane16 = tid & 15;
  const int rloc = tid >> 4;            // 0..31 local gate row
  const int jloc = rloc & 7;
  const int gate = rloc >> 3;           // i,f,g,o
  const int grow = gate * HID + wgl * 8 + jloc;

  __shared__ float lds_x[2][HID];
  __shared__ float lds_h[HID];
  __shared__ float lds_g[32];
  __shared__ float lds_c[8];

  const float* Wi = isL0 ? Wi0 : Wi1;
  const float* Wh = isL0 ? Wh0 : Wh1;
  const float breg = (isL0 ? (bi0[grow] + bh0[grow]) : (bi1[grow] + bh1[grow]));

  f32x4 Wir[16], Whr[16];
  {
    const f32x4* wi = (const f32x4*)(Wi + (size_t)grow * HID);
    const f32x4* wh = (const f32x4*)(Wh + (size_t)grow * HID);
#pragma unroll
    for (int i = 0; i < 16; ++i) {
      Wir[i] = wi[lane16 + i * 16];
      Whr[i] = wh[lane16 + i * 16];
    }
  }

  {
    const float* hini = isL0 ? h00 : h01;
    const float* cini = isL0 ? c00 : c01;
    if (tid < 8) lds_c[tid] = cini[wgl * 8 + tid];
    if (tid < 256) ((float4*)lds_h)[tid] = ((const float4*)hini)[tid];
    if (isL0 && tid < 256) {
      int tok = toks[0];
      ((float4*)lds_x[0])[tid] = ((const float4*)(emb + (size_t)tok * HID))[tid];
    }
  }
  __syncthreads();

  ull* s_mine = isL0 ? s0 : s1;

  for (int t = 0; t < T; ++t) {
    const int cur = t & 1;

    // ---- stage step inputs (each thread owns slot `tid` = h pair 2tid,2tid+1) ----
    if (isL0) {
      if (t > 0) {
        ull v = pollpipe1(s0 + (size_t)(t - 1) * SLOTS + tid, (u32)t);
        lds_h[2 * tid]     = bf16tof((u32)v & 0xFFFFu);
        lds_h[2 * tid + 1] = bf16tof(((u32)v >> 16) & 0xFFFFu);
      }
    } else {
      if (t == 0) {
        ull v = pollpipe1(s0 + tid, 1u);
        lds_x[0][2 * tid]     = bf16tof((u32)v & 0xFFFFu);
        lds_x[0][2 * tid + 1] = bf16tof(((u32)v >> 16) & 0xFFFFu);
      } else {
        ull vh;
        ull vx = pollpipe1h(s0 + (size_t)t * SLOTS + tid, (u32)(t + 1),
                            s1 + (size_t)(t - 1) * SLOTS + tid, vh);
        if (!__all((u32)(vh >> 32) >= (u32)t))      // rare: h not yet published
          vh = pollpipe1(s1 + (size_t)(t - 1) * SLOTS + tid, (u32)t);
        lds_x[0][2 * tid]     = bf16tof((u32)vx & 0xFFFFu);
        lds_x[0][2 * tid + 1] = bf16tof(((u32)vx >> 16) & 0xFFFFu);
        lds_h[2 * tid]        = bf16tof((u32)vh & 0xFFFFu);
        lds_h[2 * tid + 1]    = bf16tof(((u32)vh >> 16) & 0xFFFFu);
      }
    }
    __syncthreads();

    // L0: prefetch x_{t+1} after the poll barrier (retires under compute)
    if (isL0 && tid < 256 && t + 1 < T) {
      int tok = toks[t + 1];
      ((float4*)lds_x[cur ^ 1])[tid] = ((const float4*)(emb + (size_t)tok * HID))[tid];
    }

    // ---- fused gate dot: Wi@x + Wh@h ----
    const float* xbuf = isL0 ? lds_x[cur] : lds_x[0];
    float p0 = 0.f, p1 = 0.f, p2 = 0.f, p3 = 0.f;
#pragma unroll
    for (int i = 0; i < 16; ++i) {
      const float4 xv = *(const float4*)&xbuf[(lane16 << 2) + (i << 6)];
      p0 = fmaf(Wir[i].x, xv.x, p0);
      p1 = fmaf(Wir[i].y, xv.y, p1);
      p2 = fmaf(Wir[i].z, xv.z, p2);
      p3 = fmaf(Wir[i].w, xv.w, p3);
    }
#pragma unroll
    for (int i = 0; i < 16; ++i) {
      const float4 hv = *(const float4*)&lds_h[(lane16 << 2) + (i << 6)];
      p0 = fmaf(Whr[i].x, hv.x, p0);
      p1 = fmaf(Whr[i].y, hv.y, p1);
      p2 = fmaf(Whr[i].z, hv.z, p2);
      p3 = fmaf(Whr[i].w, hv.w, p3);
    }
    float sum = (p0 + p1) + (p2 + p3);
    sum += __shfl_xor(sum, 1);
    sum += __shfl_xor(sum, 2);
    sum += __shfl_xor(sum, 4);
    sum += __shfl_xor(sum, 8);
    if (lane16 == 0) lds_g[rloc] = sum + breg;
    __syncthreads();

    // ---- gate epilogue: 2 units/thread -> one packed bf16-pair slot ----
    if (tid < 4) {
      const int u0 = 2 * tid;
      const float c0v = fsig_(lds_g[8 + u0]) * lds_c[u0]
                      + fsig_(lds_g[u0]) * ftanh_(lds_g[16 + u0]);
      const float h0v = fsig_(lds_g[24 + u0]) * ftanh_(c0v);
      const float c1v = fsig_(lds_g[9 + u0]) * lds_c[u0 + 1]
                      + fsig_(lds_g[1 + u0]) * ftanh_(lds_g[17 + u0]);
      const float h1v = fsig_(lds_g[25 + u0]) * ftanh_(c1v);
      lds_c[u0] = c0v; lds_c[u0 + 1] = c1v;
      const int col = wgl * 8 + u0;
      const ull pk = ((ull)(u32)(t + 1) << 32)
                   | (ull)(bf16rne(h0v) | (bf16rne(h1v) << 16));
      __hip_atomic_store(&s_mine[(size_t)t * SLOTS + wgl * 4 + tid], pk,
                         __ATOMIC_RELAXED, __HIP_MEMORY_SCOPE_AGENT);
      if (!isL0 && dec_out) {                    // f32 h for the logits GEMM
        dec_out[(size_t)t * HID + col]     = h0v;
        dec_out[(size_t)t * HID + col + 1] = h1v;
      }
      if (t == T - 1) {
        if (isL0) {
          if (hf0) { hf0[col] = h0v; hf0[col + 1] = h1v; }
          if (cf0) { cf0[col] = c0v; cf0[col + 1] = c1v; }
        } else {
          if (hf1) { hf1[col] = h0v; hf1[col + 1] = h1v; }
          if (cf1) { cf1[col] = c0v; cf1[col + 1] = c1v; }
        }
      }
    }
    // no trailing barrier: next step's post-poll barrier orders LDS reuse
  }
}

// ---------------- launch ----------------
extern "C" void kernel_launch(void* const* d_in, const int* in_sizes, int n_in,
                              void* d_out, int out_size, void* d_ws, size_t ws_size,
                              hipStream_t stream) {
  const int*   inputs  = (const int*)d_in[0];
  const int*   outputs = (const int*)d_in[1];
  const int*   sos     = (const int*)d_in[2];
  const float* enc_emb = (const float*)d_in[3];
  const float* dec_emb = (const float*)d_in[4];
  const float* enc_Wih = (const float*)d_in[5];
  const float* enc_Whh = (const float*)d_in[6];
  const float* enc_bih = (const float*)d_in[7];
  const float* enc_bhh = (const float*)d_in[8];
  const float* dec_Wih = (const float*)d_in[9];
  const float* dec_Whh = (const float*)d_in[10];
  const float* dec_bih = (const float*)d_in[11];
  const float* dec_bhh = (const float*)d_in[12];
  const float* lin_W   = (const float*)d_in[13];
  const float* lin_b   = (const float*)d_in[14];

  float* out = (float*)d_out;
  // d_out scratch: 4 packed streams (8 MB each = [2048][512] ull), all dead
  // before the logits GEMM writes.
  ull* s0e = (ull*)d_out;
  ull* s1e = s0e + (size_t)T_LEN * SLOTS;
  ull* s0d = s1e + (size_t)T_LEN * SLOTS;
  ull* s1d = s0d + (size_t)T_LEN * SLOTS;

  char* ws = (char*)d_ws;
  float* zerosv = (float*)(ws + 0);
  float* hf0    = (float*)(ws + 4096);
  float* cf0    = (float*)(ws + 8192);
  float* hf1    = (float*)(ws + 12288);
  float* cf1    = (float*)(ws + 16384);
  int*   dtoks  = (int*)(ws + 20480);
  float* B2     = (float*)(ws + ((size_t)1 << 20));    // 8 MB: dec_out f32
  u16*   Xhi    = (u16*)(ws + ((size_t)10 << 20));     // 4 MB
  u16*   Xlo    = (u16*)(ws + ((size_t)15 << 20));     // 4 MB

  const size_t WOFF = (size_t)GATES * HID;

  // zero stream tags (32 MB in d_out) + zeros vector; every call (graph replay)
  zero_f4<<<2048, 256, 0, stream>>>((float4*)d_out, 2097152);
  zero_f4<<<1, 256, 0, stream>>>((float4*)zerosv, 256);
  build_dec_tokens<<<8, 256, 0, stream>>>(outputs, sos, dtoks, T_LEN);

  // encoder: both layers, fused Wi@x, layer-pipelined
  lstm2<<<256, 512, 0, stream>>>(
      enc_emb, inputs,
      enc_Wih, enc_Whh, enc_bih, enc_bhh,
      enc_Wih + WOFF, enc_Whh + WOFF, enc_bih + GATES, enc_bhh + GATES,
      zerosv, zerosv, zerosv, zerosv,
      s0e, s1e, hf0, cf0, hf1, cf1, nullptr, S_LEN);

  // decoder: init from encoder finals; layer-1 h also written plain f32 to B2
  lstm2<<<256, 512, 0, stream>>>(
      dec_emb, dtoks,
      dec_Wih, dec_Whh, dec_bih, dec_bhh,
      dec_Wih + WOFF, dec_Whh + WOFF, dec_bih + GATES, dec_bhh + GATES,
      hf0, cf0, hf1, cf1,
      s0d, s1d, nullptr, nullptr, nullptr, nullptr, B2, T_LEN);

  // logits: split X to bf16 hi/lo, then 3-term split-bf16 MFMA GEMM
  xsplit<<<(T_LEN * HID + 255) / 256, 256, 0, stream>>>(B2, Xhi, Xlo, T_LEN * HID);
  dim3 gemmV_grid((VOCAB + 63) / 64, T_LEN / 128);
  gemm_logits<<<gemmV_grid, 256, 0, stream>>>(Xhi, Xlo, lin_W, lin_b, out,
                                              T_LEN, VOCAB, HID);
}